// Round 1
// baseline (336.577 us; speedup 1.0000x reference)
//
#include <hip/hip_runtime.h>
#include <math.h>

// Problem constants (from reference)
#define BB   8      // batch
#define MM   4      // MAXM
#define DD   128    // DIM
#define NHH  8      // heads
#define QDD  16     // head dim
#define NN   256    // H*W
#define KO   128    // NH*QD

// ---------------------------------------------------------------------------
// Kernel 0: pe tables.  pe[m,i,j] = exp(i*m*theta(i,j)), theta = atan2(dy,dx)
// Stored twice: peIJ[(m*N+i)*N+j] (coalesced over j) and peT[(m*N+j)*N+i]
// (coalesced over i).
// ---------------------------------------------------------------------------
__global__ void pe_kernel(float2* __restrict__ peIJ, float2* __restrict__ peT) {
    int bid = blockIdx.x;           // m*N + i
    int m = bid >> 8;
    int i = bid & 255;
    int j = threadIdx.x;
    float dy = (float)((j >> 4) - (i >> 4));
    float dx = (float)((j & 15) - (i & 15));
    float th = atan2f(dy, dx);
    float s, c;
    sincosf((float)m * th, &s, &c);
    peIJ[(m * NN + i) * NN + j] = make_float2(c, s);
    peT[(m * NN + j) * NN + i] = make_float2(c, s);
}

// ---------------------------------------------------------------------------
// Kernel 1: E[t,b,m,h,q,n] = sum_D emb[t,m,h,q,D] * x[b,m,D,n]   (complex)
// One block per (t,b,m,h); thread = n; emb tile staged in LDS.
// ---------------------------------------------------------------------------
__global__ void e_kernel(const float* __restrict__ xr, const float* __restrict__ xi,
                         const float* __restrict__ er, const float* __restrict__ ei,
                         float2* __restrict__ E) {
    int bid = blockIdx.x;
    int h = bid & 7;  bid >>= 3;
    int m = bid & 3;  bid >>= 2;
    int b = bid & 7;  bid >>= 3;
    int t = bid;                          // 0..2
    int n = threadIdx.x;

    __shared__ float2 semb[QDD][DD];      // 16 KB
    int base = (((t * MM + m) * NHH + h) * QDD) * DD;
    for (int idx = threadIdx.x; idx < QDD * DD; idx += 256) {
        semb[idx >> 7][idx & 127] = make_float2(er[base + idx], ei[base + idx]);
    }
    __syncthreads();

    float accr[QDD], acci[QDD];
#pragma unroll
    for (int q = 0; q < QDD; ++q) { accr[q] = 0.f; acci[q] = 0.f; }

    const float* xrp = xr + (size_t)((b * MM + m) * DD) * NN + n;
    const float* xip = xi + (size_t)((b * MM + m) * DD) * NN + n;
    for (int D = 0; D < DD; ++D) {
        float vr = xrp[D * NN];
        float vi = xip[D * NN];
#pragma unroll
        for (int q = 0; q < QDD; ++q) {
            float2 e = semb[q][D];
            accr[q] = fmaf(e.x, vr, fmaf(-e.y, vi, accr[q]));
            acci[q] = fmaf(e.x, vi, fmaf( e.y, vr, acci[q]));
        }
    }
    size_t ebase = (size_t)((((t * BB + b) * MM + m) * NHH + h) * QDD) * NN + n;
#pragma unroll
    for (int q = 0; q < QDD; ++q) E[ebase + q * NN] = make_float2(accr[q], acci[q]);
}

// ---------------------------------------------------------------------------
// Kernel 2: QE[b,m,h,i] = sum_q conj(E0[b,m,h,q,i]) * enc0[m,h,q]
// Block per (b,m,h); thread = i.
// ---------------------------------------------------------------------------
__global__ void qe_kernel(const float2* __restrict__ E,
                          const float* __restrict__ encr, const float* __restrict__ enci,
                          float2* __restrict__ QE) {
    int bid = blockIdx.x;                 // (b*MM+m)*NHH + h
    int i = threadIdx.x;
    const float2* e0 = E + (size_t)(bid) * QDD * NN;   // t=0 plane: (((b*M+m)*NH+h)*QD)*N
    int h = bid & 7;
    int bm = bid >> 3;
    int m = bm & 3;
    int encbase = (m * NHH + h) * QDD;    // enc[0,m,h,0,q,0]
    float ar = 0.f, ai = 0.f;
#pragma unroll
    for (int q = 0; q < QDD; ++q) {
        float2 e = e0[q * NN + i];
        float cr = encr[encbase + q], ci = enci[encbase + q];
        // conj(e) * enc
        ar = fmaf(e.x, cr, fmaf( e.y, ci, ar));
        ai = fmaf(e.x, ci, fmaf(-e.y, cr, ai));
    }
    QE[(size_t)bid * NN + i] = make_float2(ar, ai);
}

// ---------------------------------------------------------------------------
// Kernel 3: A[b,h,i,j] = sum_m [ sum_q conj(E0[b,m,h,q,i])*K[b,m,h,q,j]
//                                + QE[b,m,h,i]*pe[m,i,j] ]
// Block per (b,h,i); thread = j.  E0/QE reads are block-uniform (scalar).
// ---------------------------------------------------------------------------
__global__ void a_kernel(const float2* __restrict__ E, const float2* __restrict__ QE,
                         const float2* __restrict__ peIJ, float2* __restrict__ A) {
    int bid = blockIdx.x;                 // (b*NHH+h)*NN + i
    int i = bid & 255;
    int bh = bid >> 8;
    int h = bh & 7;
    int b = bh >> 3;
    int j = threadIdx.x;

    float ar = 0.f, ai = 0.f;
    for (int m = 0; m < MM; ++m) {
        const float2* e0 = E + (size_t)((((0 * BB + b) * MM + m) * NHH + h) * QDD) * NN;
        const float2* kk = E + (size_t)((((1 * BB + b) * MM + m) * NHH + h) * QDD) * NN;
#pragma unroll
        for (int q = 0; q < QDD; ++q) {
            float2 e = e0[q * NN + i];    // uniform -> scalar broadcast
            float2 k = kk[q * NN + j];    // coalesced
            // conj(e)*k
            ar = fmaf(e.x, k.x, fmaf( e.y, k.y, ar));
            ai = fmaf(e.x, k.y, fmaf(-e.y, k.x, ai));
        }
        float2 qe = QE[(size_t)((b * MM + m) * NHH + h) * NN + i];  // uniform
        float2 p  = peIJ[(size_t)(m * NN + i) * NN + j];            // coalesced
        ar = fmaf(qe.x, p.x, fmaf(-qe.y, p.y, ar));
        ai = fmaf(qe.x, p.y, fmaf( qe.y, p.x, ai));
    }
    A[(size_t)bid * NN + j] = make_float2(ar, ai);
}

// ---------------------------------------------------------------------------
// Kernel 4: row softmax of |A|/4 over j; writes TRANSPOSED Aw:
//   AwT[(bh*N + j)*N + i]  (only the transpose is consumed downstream)
// Block per row (b,h,i); thread = j.
// ---------------------------------------------------------------------------
__global__ void softmax_kernel(const float2* __restrict__ A, float* __restrict__ AwT) {
    int row = blockIdx.x;                 // (b*NHH+h)*NN + i
    int j = threadIdx.x;
    float2 a = A[(size_t)row * NN + j];
    float v = sqrtf(fmaf(a.x, a.x, a.y * a.y)) * 0.25f;

    __shared__ float smax[4];
    __shared__ float ssum[4];
    int lane = threadIdx.x & 63;
    int wid  = threadIdx.x >> 6;

    float mv = v;
#pragma unroll
    for (int off = 32; off > 0; off >>= 1) mv = fmaxf(mv, __shfl_xor(mv, off));
    if (lane == 0) smax[wid] = mv;
    __syncthreads();
    float mx = fmaxf(fmaxf(smax[0], smax[1]), fmaxf(smax[2], smax[3]));

    float e = expf(v - mx);
    float sv = e;
#pragma unroll
    for (int off = 32; off > 0; off >>= 1) sv += __shfl_xor(sv, off);
    if (lane == 0) ssum[wid] = sv;
    __syncthreads();
    float sum = ssum[0] + ssum[1] + ssum[2] + ssum[3];

    float aw = e / sum;
    int bh = row >> 8;
    int i  = row & 255;
    AwT[(size_t)(bh * NN + j) * NN + i] = aw;
}

// ---------------------------------------------------------------------------
// Kernel 5: res[b,m,h,q,i] = sum_j V[b,m,h,q,j]*Aw[b,h,i,j]
//                           + enc1[m,h,q]*PA[b,m,h,i],
//           PA[b,m,h,i] = sum_j pe[m,i,j]*Aw[b,h,i,j]   (fused)
// Block per (b,m,h); thread = i; V staged in LDS (32 KB).
// Output layout res[((b*M+m)*KO + h*QD + q)*N + i]  for the final GEMM.
// ---------------------------------------------------------------------------
__global__ void res_kernel(const float2* __restrict__ E, const float* __restrict__ AwT,
                           const float2* __restrict__ peT,
                           const float* __restrict__ encr, const float* __restrict__ enci,
                           float2* __restrict__ Res) {
    int bid = blockIdx.x;                 // (b*MM+m)*NHH + h
    int h = bid & 7;
    int bm = bid >> 3;
    int m = bm & 3;
    int b = bm >> 2;
    int i = threadIdx.x;

    __shared__ float2 sv[QDD][NN];        // 32 KB
    __shared__ float2 senc[QDD];
    const float2* V = E + (size_t)((((2 * BB + b) * MM + m) * NHH + h) * QDD) * NN;
    for (int idx = threadIdx.x; idx < QDD * NN; idx += 256) sv[idx >> 8][idx & 255] = V[idx];
    if (threadIdx.x < QDD) {
        int eb = ((MM + m) * NHH + h) * QDD + threadIdx.x;   // enc[1,...]
        senc[threadIdx.x] = make_float2(encr[eb], enci[eb]);
    }
    __syncthreads();

    float accr[QDD], acci[QDD];
#pragma unroll
    for (int q = 0; q < QDD; ++q) { accr[q] = 0.f; acci[q] = 0.f; }
    float par = 0.f, pai = 0.f;

    const float*  awp = AwT + (size_t)((b * NHH + h) * NN) * NN + i;
    const float2* pep = peT + (size_t)(m * NN) * NN + i;
    for (int j = 0; j < NN; ++j) {
        float aw  = awp[(size_t)j * NN];      // coalesced
        float2 p  = pep[(size_t)j * NN];      // coalesced
        par = fmaf(p.x, aw, par);
        pai = fmaf(p.y, aw, pai);
#pragma unroll
        for (int q = 0; q < QDD; ++q) {
            float2 v = sv[q][j];              // LDS broadcast
            accr[q] = fmaf(v.x, aw, accr[q]);
            acci[q] = fmaf(v.y, aw, acci[q]);
        }
    }

    float2* rp = Res + (size_t)((b * MM + m) * KO + h * QDD) * NN + i;
#pragma unroll
    for (int q = 0; q < QDD; ++q) {
        float2 e1 = senc[q];
        float rr = accr[q] + e1.x * par - e1.y * pai;
        float ri = acci[q] + e1.x * pai + e1.y * par;
        rp[(size_t)q * NN] = make_float2(rr, ri);
    }
}

// ---------------------------------------------------------------------------
// Kernel 6: out[b,m,D,n] = sum_k w_out[m,D,k]*res[b,m,k,n]; split re/im halves.
// Block per (b,m,D); thread = n; w_out row staged in LDS.
// ---------------------------------------------------------------------------
__global__ void out_kernel(const float2* __restrict__ Res,
                           const float* __restrict__ wor, const float* __restrict__ woi,
                           float* __restrict__ out) {
    int bid = blockIdx.x;                 // (b*MM+m)*DD + D
    int D = bid & 127;
    int bm = bid >> 7;
    int n = threadIdx.x;

    __shared__ float2 sw[KO];
    int wb = ((bm & 3) * DD + D) * KO;    // m = bm & 3
    if (threadIdx.x < KO) sw[threadIdx.x] = make_float2(wor[wb + threadIdx.x], woi[wb + threadIdx.x]);
    __syncthreads();

    const float2* rp = Res + (size_t)(bm * KO) * NN + n;
    float ar = 0.f, ai = 0.f;
#pragma unroll 8
    for (int k = 0; k < KO; ++k) {
        float2 r = rp[(size_t)k * NN];
        float2 w = sw[k];
        ar = fmaf(w.x, r.x, fmaf(-w.y, r.y, ar));
        ai = fmaf(w.x, r.y, fmaf( w.y, r.x, ai));
    }
    size_t ob = (size_t)(bm * DD + D) * NN + n;
    out[ob] = ar;
    out[(size_t)BB * MM * DD * NN + ob] = ai;
}

// ---------------------------------------------------------------------------
extern "C" void kernel_launch(void* const* d_in, const int* in_sizes, int n_in,
                              void* d_out, int out_size, void* d_ws, size_t ws_size,
                              hipStream_t stream) {
    (void)in_sizes; (void)n_in; (void)out_size; (void)ws_size;

    const float* x_re   = (const float*)d_in[0];
    const float* x_im   = (const float*)d_in[1];
    const float* emb_re = (const float*)d_in[2];
    const float* emb_im = (const float*)d_in[3];
    const float* enc_re = (const float*)d_in[4];
    const float* enc_im = (const float*)d_in[5];
    const float* out_re = (const float*)d_in[6];
    const float* out_im = (const float*)d_in[7];
    float* out = (float*)d_out;

    // Workspace layout (floats). Total ~155.7 MB.
    float* ws = (float*)d_ws;
    size_t off = 0;
    float2* peIJ = (float2*)(ws + off); off += (size_t)MM * NN * NN * 2;          // 524288
    float2* peT  = (float2*)(ws + off); off += (size_t)MM * NN * NN * 2;          // 524288
    float2* E    = (float2*)(ws + off); off += (size_t)3 * BB * MM * NHH * QDD * NN * 2; // 25165824
    float2* QE   = (float2*)(ws + off); off += (size_t)BB * MM * NHH * NN * 2;    // 131072
    float2* A    = (float2*)(ws + off); off += (size_t)BB * NHH * NN * NN * 2;    // 8388608
    float*  AwT  = (float*)(ws + off);  off += (size_t)BB * NHH * NN * NN;        // 4194304
    float2* Res  = A;  // alias: A is dead after softmax; Res needs 2097152 floats

    pe_kernel<<<MM * NN, 256, 0, stream>>>(peIJ, peT);
    e_kernel<<<3 * BB * MM * NHH, 256, 0, stream>>>(x_re, x_im, emb_re, emb_im, E);
    qe_kernel<<<BB * MM * NHH, 256, 0, stream>>>(E, enc_re, enc_im, QE);
    a_kernel<<<BB * NHH * NN, 256, 0, stream>>>(E, QE, peIJ, A);
    softmax_kernel<<<BB * NHH * NN, 256, 0, stream>>>(A, AwT);
    res_kernel<<<BB * MM * NHH, 256, 0, stream>>>(E, AwT, peT, enc_re, enc_im, Res);
    out_kernel<<<BB * MM * DD, 256, 0, stream>>>(Res, out_re, out_im, out);
}

// Round 3
// 190.890 us; speedup vs baseline: 1.7632x; 1.7632x over previous
//
#include <hip/hip_runtime.h>
#include <math.h>

// Problem constants (from reference)
#define BB   8      // batch
#define MM   4      // MAXM
#define DD   128    // DIM
#define NHH  8      // heads
#define QDD  16     // head dim
#define NN   256    // H*W
#define KO   128    // NH*QD
#define ATILE 16    // i-rows per a_kernel block
#define DTILE 4     // D-rows per out_kernel block

// ---------------------------------------------------------------------------
// Kernel 0: pe tables.  pe[m,i,j] = exp(i*m*theta(i,j)), theta = atan2(dy,dx)
// Stored twice: peIJ[(m*N+i)*N+j] (coalesced over j) and peT[(m*N+j)*N+i]
// (coalesced over i).
// ---------------------------------------------------------------------------
__global__ void pe_kernel(float2* __restrict__ peIJ, float2* __restrict__ peT) {
    int bid = blockIdx.x;           // m*N + i
    int m = bid >> 8;
    int i = bid & 255;
    int j = threadIdx.x;
    float dy = (float)((j >> 4) - (i >> 4));
    float dx = (float)((j & 15) - (i & 15));
    float th = atan2f(dy, dx);
    float s, c;
    sincosf((float)m * th, &s, &c);
    peIJ[(m * NN + i) * NN + j] = make_float2(c, s);
    peT[(m * NN + j) * NN + i] = make_float2(c, s);
}

// ---------------------------------------------------------------------------
// Kernel 1: E[t,b,m,h,q,n] = sum_D emb[t,m,h,q,D] * x[b,m,D,n]   (complex)
// One block per (t,b,m,h); thread = n; emb tile staged in LDS.
// ---------------------------------------------------------------------------
__global__ void e_kernel(const float* __restrict__ xr, const float* __restrict__ xi,
                         const float* __restrict__ er, const float* __restrict__ ei,
                         float2* __restrict__ E) {
    int bid = blockIdx.x;
    int h = bid & 7;  bid >>= 3;
    int m = bid & 3;  bid >>= 2;
    int b = bid & 7;  bid >>= 3;
    int t = bid;                          // 0..2
    int n = threadIdx.x;

    __shared__ float2 semb[QDD][DD];      // 16 KB
    int base = (((t * MM + m) * NHH + h) * QDD) * DD;
    for (int idx = threadIdx.x; idx < QDD * DD; idx += 256) {
        semb[idx >> 7][idx & 127] = make_float2(er[base + idx], ei[base + idx]);
    }
    __syncthreads();

    float accr[QDD], acci[QDD];
#pragma unroll
    for (int q = 0; q < QDD; ++q) { accr[q] = 0.f; acci[q] = 0.f; }

    const float* xrp = xr + (size_t)((b * MM + m) * DD) * NN + n;
    const float* xip = xi + (size_t)((b * MM + m) * DD) * NN + n;
    for (int D = 0; D < DD; ++D) {
        float vr = xrp[D * NN];
        float vi = xip[D * NN];
#pragma unroll
        for (int q = 0; q < QDD; ++q) {
            float2 e = semb[q][D];
            accr[q] = fmaf(e.x, vr, fmaf(-e.y, vi, accr[q]));
            acci[q] = fmaf(e.x, vi, fmaf( e.y, vr, acci[q]));
        }
    }
    size_t ebase = (size_t)((((t * BB + b) * MM + m) * NHH + h) * QDD) * NN + n;
#pragma unroll
    for (int q = 0; q < QDD; ++q) E[ebase + q * NN] = make_float2(accr[q], acci[q]);
}

// ---------------------------------------------------------------------------
// Kernel 2: QE[b,m,h,i] = sum_q conj(E0[b,m,h,q,i]) * enc0[m,h,q]
// Block per (b,m,h); thread = i.
// ---------------------------------------------------------------------------
__global__ void qe_kernel(const float2* __restrict__ E,
                          const float* __restrict__ encr, const float* __restrict__ enci,
                          float2* __restrict__ QE) {
    int bid = blockIdx.x;                 // (b*MM+m)*NHH + h
    int i = threadIdx.x;
    const float2* e0 = E + (size_t)(bid) * QDD * NN;   // t=0 plane
    int h = bid & 7;
    int bm = bid >> 3;
    int m = bm & 3;
    int encbase = (m * NHH + h) * QDD;    // enc[0,m,h,0,q,0]
    float ar = 0.f, ai = 0.f;
#pragma unroll
    for (int q = 0; q < QDD; ++q) {
        float2 e = e0[q * NN + i];
        float cr = encr[encbase + q], ci = enci[encbase + q];
        // conj(e) * enc
        ar = fmaf(e.x, cr, fmaf( e.y, ci, ar));
        ai = fmaf(e.x, ci, fmaf(-e.y, cr, ai));
    }
    QE[(size_t)bid * NN + i] = make_float2(ar, ai);
}

// ---------------------------------------------------------------------------
// Kernel 3 (v2, register-tiled): A[b,h,i,j] =
//   sum_m [ sum_q conj(E0[b,m,h,q,i])*K[b,m,h,q,j] + QE[b,m,h,i]*pe[m,i,j] ]
// Block = (b,h, itile of 16 rows); thread = j.  K tile staged in LDS once per
// (block, m) and held per-column in registers; e0/QE broadcast from LDS.
// L2 traffic drops 16x vs v1; kernel becomes VALU-bound.
// ---------------------------------------------------------------------------
__global__ void a_kernel(const float2* __restrict__ E, const float2* __restrict__ QE,
                         const float2* __restrict__ peIJ, float2* __restrict__ A) {
    int bid = blockIdx.x;                 // (b*NHH+h)*16 + itile
    int itile = bid & 15;
    int bh = bid >> 4;
    int h = bh & 7;
    int b = bh >> 3;
    int j = threadIdx.x;
    int i0 = itile * ATILE;

    __shared__ float2 sk[QDD][NN];        // 32 KB
    __shared__ float2 se[ATILE][QDD];     // 2 KB, [r][q] so q-reads vectorize
    __shared__ float2 sqe[ATILE];

    float ar[ATILE], ai[ATILE];
#pragma unroll
    for (int r = 0; r < ATILE; ++r) { ar[r] = 0.f; ai[r] = 0.f; }

    for (int m = 0; m < MM; ++m) {
        const float2* kk = E + (size_t)((((BB + b) * MM + m) * NHH + h) * QDD) * NN; // t=1
        const float2* e0 = E + (size_t)(((b * MM + m) * NHH + h) * QDD) * NN;        // t=0
        __syncthreads();
        for (int idx = threadIdx.x; idx < QDD * NN; idx += 256)
            sk[idx >> 8][idx & 255] = kk[idx];
        {
            int q = threadIdx.x & 15;
            int r = threadIdx.x >> 4;     // 0..15
            se[r][q] = e0[q * NN + i0 + r];
        }
        if (threadIdx.x < ATILE)
            sqe[threadIdx.x] = QE[(size_t)((b * MM + m) * NHH + h) * NN + i0 + threadIdx.x];
        __syncthreads();

        // this thread's K column into registers
        float2 kreg[QDD];
#pragma unroll
        for (int q = 0; q < QDD; ++q) kreg[q] = sk[q][j];

#pragma unroll
        for (int r = 0; r < ATILE; ++r) {
#pragma unroll
            for (int q = 0; q < QDD; ++q) {
                float2 e = se[r][q];      // block-uniform broadcast
                ar[r] = fmaf(e.x, kreg[q].x, fmaf( e.y, kreg[q].y, ar[r]));
                ai[r] = fmaf(e.x, kreg[q].y, fmaf(-e.y, kreg[q].x, ai[r]));
            }
            float2 p  = peIJ[(size_t)(m * NN + i0 + r) * NN + j];   // coalesced
            float2 qe = sqe[r];
            ar[r] = fmaf(qe.x, p.x, fmaf(-qe.y, p.y, ar[r]));
            ai[r] = fmaf(qe.x, p.y, fmaf( qe.y, p.x, ai[r]));
        }
    }
#pragma unroll
    for (int r = 0; r < ATILE; ++r)
        A[(size_t)(bh * NN + i0 + r) * NN + j] = make_float2(ar[r], ai[r]);
}

// ---------------------------------------------------------------------------
// Kernel 4: row softmax of |A|/4 over j; writes TRANSPOSED Aw:
//   AwT[(bh*N + j)*N + i]  (only the transpose is consumed downstream)
// ---------------------------------------------------------------------------
__global__ void softmax_kernel(const float2* __restrict__ A, float* __restrict__ AwT) {
    int row = blockIdx.x;                 // (b*NHH+h)*NN + i
    int j = threadIdx.x;
    float2 a = A[(size_t)row * NN + j];
    float v = sqrtf(fmaf(a.x, a.x, a.y * a.y)) * 0.25f;

    __shared__ float smax[4];
    __shared__ float ssum[4];
    int lane = threadIdx.x & 63;
    int wid  = threadIdx.x >> 6;

    float mv = v;
#pragma unroll
    for (int off = 32; off > 0; off >>= 1) mv = fmaxf(mv, __shfl_xor(mv, off));
    if (lane == 0) smax[wid] = mv;
    __syncthreads();
    float mx = fmaxf(fmaxf(smax[0], smax[1]), fmaxf(smax[2], smax[3]));

    float e = expf(v - mx);
    float sv = e;
#pragma unroll
    for (int off = 32; off > 0; off >>= 1) sv += __shfl_xor(sv, off);
    if (lane == 0) ssum[wid] = sv;
    __syncthreads();
    float sum = ssum[0] + ssum[1] + ssum[2] + ssum[3];

    float aw = e / sum;
    int bh = row >> 8;
    int i  = row & 255;
    AwT[(size_t)(bh * NN + j) * NN + i] = aw;
}

// ---------------------------------------------------------------------------
// Kernel 5 (v2, 512 threads, j-split): res[b,m,h,q,i] =
//   sum_j V[b,m,h,q,j]*Aw[b,h,i,j] + enc1[m,h,q]*PA[b,m,h,i],
//   PA[b,m,h,i] = sum_j pe[m,i,j]*Aw[b,h,i,j]   (fused, linear in j-halves)
// Two 256-thread groups each take half the j-range; LDS reduce at the end.
// ---------------------------------------------------------------------------
__global__ __launch_bounds__(512)
void res_kernel(const float2* __restrict__ E, const float* __restrict__ AwT,
                const float2* __restrict__ peT,
                const float* __restrict__ encr, const float* __restrict__ enci,
                float2* __restrict__ Res) {
    int bid = blockIdx.x;                 // (b*MM+m)*NHH + h
    int h = bid & 7;
    int bm = bid >> 3;
    int m = bm & 3;
    int b = bm >> 2;
    int i = threadIdx.x & 255;
    int g = threadIdx.x >> 8;             // 0 or 1

    __shared__ float2 sv[QDD][NN];        // 32 KB
    __shared__ float2 spart[NN][QDD + 1]; // 34 KB partials from group 1
    __shared__ float2 senc[QDD];

    const float2* V = E + (size_t)((((2 * BB + b) * MM + m) * NHH + h) * QDD) * NN;
    for (int idx = threadIdx.x; idx < QDD * NN; idx += 512) sv[idx >> 8][idx & 255] = V[idx];
    if (threadIdx.x < QDD) {
        int eb = ((MM + m) * NHH + h) * QDD + threadIdx.x;   // enc[1,...]
        senc[threadIdx.x] = make_float2(encr[eb], enci[eb]);
    }
    __syncthreads();

    float accr[QDD], acci[QDD];
#pragma unroll
    for (int q = 0; q < QDD; ++q) { accr[q] = 0.f; acci[q] = 0.f; }
    float par = 0.f, pai = 0.f;

    const float*  awp = AwT + (size_t)((b * NHH + h) * NN) * NN + i;
    const float2* pep = peT + (size_t)(m * NN) * NN + i;
    int j0 = g * (NN / 2);
    for (int j = j0; j < j0 + NN / 2; ++j) {
        float aw  = awp[(size_t)j * NN];      // coalesced over i
        float2 p  = pep[(size_t)j * NN];      // coalesced over i
        par = fmaf(p.x, aw, par);
        pai = fmaf(p.y, aw, pai);
#pragma unroll
        for (int q = 0; q < QDD; ++q) {
            float2 v = sv[q][j];              // broadcast
            accr[q] = fmaf(v.x, aw, accr[q]);
            acci[q] = fmaf(v.y, aw, acci[q]);
        }
    }

    if (g == 1) {
#pragma unroll
        for (int q = 0; q < QDD; ++q) spart[i][q] = make_float2(accr[q], acci[q]);
        spart[i][QDD] = make_float2(par, pai);
    }
    __syncthreads();
    if (g == 0) {
#pragma unroll
        for (int q = 0; q < QDD; ++q) {
            float2 o = spart[i][q];
            accr[q] += o.x; acci[q] += o.y;
        }
        float2 o = spart[i][QDD];
        par += o.x; pai += o.y;

        float2* rp = Res + (size_t)((b * MM + m) * KO + h * QDD) * NN + i;
#pragma unroll
        for (int q = 0; q < QDD; ++q) {
            float2 e1 = senc[q];
            float rr = accr[q] + e1.x * par - e1.y * pai;
            float ri = acci[q] + e1.x * pai + e1.y * par;
            rp[(size_t)q * NN] = make_float2(rr, ri);
        }
    }
}

// ---------------------------------------------------------------------------
// Kernel 6 (v2, D-tiled): out[b,m,D,n] = sum_k w_out[m,D,k]*res[b,m,k,n].
// Block = (b,m, dtile of 4 D); thread = n. Res row read once per 4 D rows.
// ---------------------------------------------------------------------------
__global__ void out_kernel(const float2* __restrict__ Res,
                           const float* __restrict__ wor, const float* __restrict__ woi,
                           float* __restrict__ out) {
    int bid = blockIdx.x;                 // (b*MM+m)*(DD/DTILE) + dtile
    int dt = bid & (DD / DTILE - 1);
    int bm = bid >> 5;                    // DD/DTILE == 32
    int n = threadIdx.x;
    int D0 = dt * DTILE;
    int m = bm & 3;

    __shared__ float2 sw[DTILE][KO];      // 4 KB
    for (int idx = threadIdx.x; idx < DTILE * KO; idx += 256) {
        int d = idx >> 7, k = idx & 127;
        int wb = (m * DD + D0 + d) * KO + k;
        sw[d][k] = make_float2(wor[wb], woi[wb]);
    }
    __syncthreads();

    const float2* rp = Res + (size_t)(bm * KO) * NN + n;
    float ar[DTILE], ai[DTILE];
#pragma unroll
    for (int d = 0; d < DTILE; ++d) { ar[d] = 0.f; ai[d] = 0.f; }

    for (int k = 0; k < KO; ++k) {
        float2 r = rp[(size_t)k * NN];    // coalesced
#pragma unroll
        for (int d = 0; d < DTILE; ++d) {
            float2 w = sw[d][k];          // broadcast
            ar[d] = fmaf(w.x, r.x, fmaf(-w.y, r.y, ar[d]));
            ai[d] = fmaf(w.x, r.y, fmaf( w.y, r.x, ai[d]));
        }
    }
#pragma unroll
    for (int d = 0; d < DTILE; ++d) {
        size_t ob = (size_t)(bm * DD + D0 + d) * NN + n;
        out[ob] = ar[d];
        out[(size_t)BB * MM * DD * NN + ob] = ai[d];
    }
}

// ---------------------------------------------------------------------------
extern "C" void kernel_launch(void* const* d_in, const int* in_sizes, int n_in,
                              void* d_out, int out_size, void* d_ws, size_t ws_size,
                              hipStream_t stream) {
    (void)in_sizes; (void)n_in; (void)out_size; (void)ws_size;

    const float* x_re   = (const float*)d_in[0];
    const float* x_im   = (const float*)d_in[1];
    const float* emb_re = (const float*)d_in[2];
    const float* emb_im = (const float*)d_in[3];
    const float* enc_re = (const float*)d_in[4];
    const float* enc_im = (const float*)d_in[5];
    const float* out_re = (const float*)d_in[6];
    const float* out_im = (const float*)d_in[7];
    float* out = (float*)d_out;

    // Workspace layout (floats). Total ~155.7 MB.
    float* ws = (float*)d_ws;
    size_t off = 0;
    float2* peIJ = (float2*)(ws + off); off += (size_t)MM * NN * NN * 2;          // 524288
    float2* peT  = (float2*)(ws + off); off += (size_t)MM * NN * NN * 2;          // 524288
    float2* E    = (float2*)(ws + off); off += (size_t)3 * BB * MM * NHH * QDD * NN * 2; // 25165824
    float2* QE   = (float2*)(ws + off); off += (size_t)BB * MM * NHH * NN * 2;    // 131072
    float2* A    = (float2*)(ws + off); off += (size_t)BB * NHH * NN * NN * 2;    // 8388608
    float*  AwT  = (float*)(ws + off);  off += (size_t)BB * NHH * NN * NN;        // 4194304
    float2* Res  = A;  // alias: A is dead after softmax; Res needs 2097152 floats

    pe_kernel<<<MM * NN, 256, 0, stream>>>(peIJ, peT);
    e_kernel<<<3 * BB * MM * NHH, 256, 0, stream>>>(x_re, x_im, emb_re, emb_im, E);
    qe_kernel<<<BB * MM * NHH, 256, 0, stream>>>(E, enc_re, enc_im, QE);
    a_kernel<<<BB * NHH * ATILE, 256, 0, stream>>>(E, QE, peIJ, A);
    softmax_kernel<<<BB * NHH * NN, 256, 0, stream>>>(A, AwT);
    res_kernel<<<BB * MM * NHH, 512, 0, stream>>>(E, AwT, peT, enc_re, enc_im, Res);
    out_kernel<<<BB * MM * (DD / DTILE), 256, 0, stream>>>(Res, out_re, out_im, out);
}